// Round 1
// baseline (88.170 us; speedup 1.0000x reference)
//
#include <hip/hip_runtime.h>

#define B_    32
#define T_    1000
#define F_    80
#define COUT_ 64
#define NAUX_ 128
#define TO_   500
#define FO_   40
#define PSTR_ 12   // per-(b,c) param stride in floats: 9 filter + 1 bias + 2 pad

// Kernel 1: hypernetwork. filt[b, c*9 + i*3 + j] = dot(aux[b], Wg[c*9+i*3+j]) + bg[...]
// bias[b,c] = dot(aux[b], Wb[c]) + bb[c].  Also l2[b] = x_len[b] >> 1 into out tail.
__global__ __launch_bounds__(256) void hyper_kernel(
    const float* __restrict__ aux,
    const float* __restrict__ Wg,
    const float* __restrict__ bg,
    const float* __restrict__ Wb,
    const float* __restrict__ bb,
    const int*   __restrict__ x_len,
    float* __restrict__ fw,      // [B*COUT*PSTR_] in d_ws
    float* __restrict__ l2_out)  // d_out + B*COUT*TO*FO
{
    const int NF = B_ * COUT_ * 9;        // 18432 filter taps
    const int NB = B_ * COUT_;            // 2048 biases
    int t = blockIdx.x * blockDim.x + threadIdx.x;

    if (t < NF) {
        int b   = t / (COUT_ * 9);
        int idx = t % (COUT_ * 9);
        const float* a = aux + b * NAUX_;
        const float* w = Wg + (size_t)idx * NAUX_;
        float s = bg[idx];
        #pragma unroll
        for (int n = 0; n < NAUX_; n += 4) {
            float4 av = *(const float4*)(a + n);
            float4 wv = *(const float4*)(w + n);
            s = fmaf(av.x, wv.x, s);
            s = fmaf(av.y, wv.y, s);
            s = fmaf(av.z, wv.z, s);
            s = fmaf(av.w, wv.w, s);
        }
        int c = idx / 9, k = idx % 9;
        fw[(b * COUT_ + c) * PSTR_ + k] = s;
    } else if (t < NF + NB) {
        int u = t - NF;
        int b = u / COUT_, c = u % COUT_;
        const float* a = aux + b * NAUX_;
        const float* w = Wb + c * NAUX_;
        float s = bb[c];
        #pragma unroll
        for (int n = 0; n < NAUX_; n += 4) {
            float4 av = *(const float4*)(a + n);
            float4 wv = *(const float4*)(w + n);
            s = fmaf(av.x, wv.x, s);
            s = fmaf(av.y, wv.y, s);
            s = fmaf(av.z, wv.z, s);
            s = fmaf(av.w, wv.w, s);
        }
        fw[u * PSTR_ + 9] = s;
    } else if (t < NF + NB + B_) {
        int b = t - NF - NB;
        int xl = x_len[b];
        l2_out[b] = (float)(xl >> 1);   // l1 = x_len; l2 = floor((l1-2)/2)+1 = x_len/2
    }
}

// Kernel 2: fused conv(3x3, pad 1) + bias + relu + maxpool(2x2 s2) + time mask.
// One thread = 4 consecutive pooled outputs along freq (one float4 store).
__global__ __launch_bounds__(256) void conv_pool_kernel(
    const float* __restrict__ x,      // [B][T][F]
    const int*   __restrict__ x_len,
    const float* __restrict__ fw,     // [B*COUT][PSTR_]
    float* __restrict__ out)          // [B][COUT][TO][FO]
{
    int tid = blockIdx.x * blockDim.x + threadIdx.x;
    // total threads = B*COUT*TO*10 = 10,240,000 (exact grid)
    int f4 = tid % 10;
    int to = (tid / 10) % TO_;
    int bc = tid / (10 * TO_);        // b*COUT + c
    int b  = bc / COUT_;

    float4* op = (float4*)(out + (size_t)tid * 4);

    int l2 = x_len[b] >> 1;
    if (to >= l2) {
        *op = make_float4(0.f, 0.f, 0.f, 0.f);
        return;
    }

    // per-(b,c) filter + bias (aligned float4 loads from padded struct)
    const float* p = fw + bc * PSTR_;
    float4 p0 = *(const float4*)(p);
    float4 p1 = *(const float4*)(p + 4);
    float4 p2 = *(const float4*)(p + 8);
    const float Flt[9] = {p0.x, p0.y, p0.z, p0.w, p1.x, p1.y, p1.z, p1.w, p2.x};
    const float bias = p2.y;

    // 4x10 input window: rows 2to-1..2to+2, cols 8f4-1..8f4+8 (zero-padded)
    float w[4][10];
    const float* xb = x + (size_t)b * (T_ * F_);
    const int cbase = 8 * f4;
    #pragma unroll
    for (int i = 0; i < 4; ++i) {
        int r = 2 * to - 1 + i;
        if (r < 0 || r >= T_) {
            #pragma unroll
            for (int j = 0; j < 10; ++j) w[i][j] = 0.f;
        } else {
            const float* rp = xb + r * F_ + cbase;      // 16B-aligned (8*f4 % 4 == 0)
            w[i][0] = (f4 > 0) ? rp[-1] : 0.f;
            float4 m0 = *(const float4*)(rp);
            float4 m1 = *(const float4*)(rp + 4);
            w[i][1] = m0.x; w[i][2] = m0.y; w[i][3] = m0.z; w[i][4] = m0.w;
            w[i][5] = m1.x; w[i][6] = m1.y; w[i][7] = m1.z; w[i][8] = m1.w;
            w[i][9] = (f4 < 9) ? rp[8] : 0.f;
        }
    }

    float o[4];
    #pragma unroll
    for (int q = 0; q < 4; ++q) {
        float s[2][2];
        #pragma unroll
        for (int dt = 0; dt < 2; ++dt) {
            #pragma unroll
            for (int df = 0; df < 2; ++df) {
                // conv at (t = 2to+dt, f = 8f4+2q+df); window rows dt..dt+2, cols 2q+df..2q+df+2
                float acc = 0.f;
                #pragma unroll
                for (int i = 0; i < 3; ++i)
                    #pragma unroll
                    for (int j = 0; j < 3; ++j)
                        acc = fmaf(Flt[i * 3 + j], w[dt + i][2 * q + df + j], acc);
                s[dt][df] = acc;
            }
        }
        float m = fmaxf(fmaxf(s[0][0], s[0][1]), fmaxf(s[1][0], s[1][1]));
        o[q] = fmaxf(m + bias, 0.f);
    }
    *op = make_float4(o[0], o[1], o[2], o[3]);
}

extern "C" void kernel_launch(void* const* d_in, const int* in_sizes, int n_in,
                              void* d_out, int out_size, void* d_ws, size_t ws_size,
                              hipStream_t stream) {
    const float* x     = (const float*)d_in[0];
    const int*   x_len = (const int*)d_in[1];
    const float* aux   = (const float*)d_in[2];
    const float* Wg    = (const float*)d_in[3];
    const float* bg    = (const float*)d_in[4];
    const float* Wb    = (const float*)d_in[5];
    const float* bb    = (const float*)d_in[6];

    float* out = (float*)d_out;
    float* fw  = (float*)d_ws;                        // B*COUT*PSTR_ floats = 98 KB
    float* l2_out = out + (size_t)B_ * COUT_ * TO_ * FO_;  // tail: 32 floats

    // Kernel 1: 18432 + 2048 + 32 = 20512 threads
    {
        int total = B_ * COUT_ * 9 + B_ * COUT_ + B_;
        int blocks = (total + 255) / 256;
        hipLaunchKernelGGL(hyper_kernel, dim3(blocks), dim3(256), 0, stream,
                           aux, Wg, bg, Wb, bb, x_len, fw, l2_out);
    }
    // Kernel 2: exact grid 10,240,000 / 256 = 40,000 blocks
    {
        int total = B_ * COUT_ * TO_ * 10;
        int blocks = total / 256;
        hipLaunchKernelGGL(conv_pool_kernel, dim3(blocks), dim3(256), 0, stream,
                           x, x_len, fw, out);
    }
}

// Round 3
// 47.880 us; speedup vs baseline: 1.8415x; 1.8415x over previous
//
#include <hip/hip_runtime.h>

#define B_    32
#define T_    1000
#define F_    80
#define COUT_ 64
#define NAUX_ 128
#define TO_   500
#define FO_   40
#define PSTR_ 12   // per-(b,c) param stride in floats: 9 filter + 1 bias + 2 pad
#define CL_   8    // channels per thread (register window reuse)

// Kernel 1: hypernetwork. filt[b, c*9 + i*3 + j] = dot(aux[b], Wg[c*9+i*3+j]) + bg[...]
// bias[b,c] = dot(aux[b], Wb[c]) + bb[c].  Also l2[b] = x_len[b] >> 1 into out tail.
__global__ __launch_bounds__(256) void hyper_kernel(
    const float* __restrict__ aux,
    const float* __restrict__ Wg,
    const float* __restrict__ bg,
    const float* __restrict__ Wb,
    const float* __restrict__ bb,
    const int*   __restrict__ x_len,
    float* __restrict__ fw,      // [B*COUT*PSTR_] in d_ws
    float* __restrict__ l2_out)  // d_out + B*COUT*TO*FO
{
    const int NF = B_ * COUT_ * 9;        // 18432 filter taps
    const int NB = B_ * COUT_;            // 2048 biases
    int t = blockIdx.x * blockDim.x + threadIdx.x;

    if (t < NF) {
        int b   = t / (COUT_ * 9);
        int idx = t % (COUT_ * 9);
        const float* a = aux + b * NAUX_;
        const float* w = Wg + (size_t)idx * NAUX_;
        float s = bg[idx];
        #pragma unroll
        for (int n = 0; n < NAUX_; n += 4) {
            float4 av = *(const float4*)(a + n);
            float4 wv = *(const float4*)(w + n);
            s = fmaf(av.x, wv.x, s);
            s = fmaf(av.y, wv.y, s);
            s = fmaf(av.z, wv.z, s);
            s = fmaf(av.w, wv.w, s);
        }
        int c = idx / 9, k = idx % 9;
        fw[(b * COUT_ + c) * PSTR_ + k] = s;
    } else if (t < NF + NB) {
        int u = t - NF;
        int b = u / COUT_, c = u % COUT_;
        const float* a = aux + b * NAUX_;
        const float* w = Wb + c * NAUX_;
        float s = bb[c];
        #pragma unroll
        for (int n = 0; n < NAUX_; n += 4) {
            float4 av = *(const float4*)(a + n);
            float4 wv = *(const float4*)(w + n);
            s = fmaf(av.x, wv.x, s);
            s = fmaf(av.y, wv.y, s);
            s = fmaf(av.z, wv.z, s);
            s = fmaf(av.w, wv.w, s);
        }
        fw[u * PSTR_ + 9] = s;
    } else if (t < NF + NB + B_) {
        int b = t - NF - NB;
        int xl = x_len[b];
        l2_out[b] = (float)(xl >> 1);   // l1 = x_len; l2 = floor((l1-2)/2)+1 = x_len/2
    }
}

// Kernel 2: fused conv(3x3, pad 1) + bias + relu + maxpool(2x2 s2) + time mask.
// One thread = one (b, to, f4) window kept in registers, looped over CL_ channels.
// Stores one float4 (4 pooled freq cols) per channel.
__global__ __launch_bounds__(256) void conv_pool_kernel(
    const float* __restrict__ x,      // [B][T][F]
    const int*   __restrict__ x_len,
    const float* __restrict__ fw,     // [B*COUT][PSTR_]
    float* __restrict__ out)          // [B][COUT][TO][FO]
{
    int tid = blockIdx.x * blockDim.x + threadIdx.x;
    // total threads = B * (COUT/CL) * TO * 10 = 1,280,000 (exact grid)
    int f4 = tid % 10;
    int to = (tid / 10) % TO_;
    int g  = (tid / (10 * TO_)) % (COUT_ / CL_);
    int b  = tid / (10 * TO_ * (COUT_ / CL_));
    int bc0 = b * COUT_ + g * CL_;

    // output col offset = 4*f4 (4 pooled cols per thread, 10 threads per row)
    float* obase = out + ((size_t)bc0 * TO_ + to) * FO_ + 4 * f4;

    int l2 = x_len[b] >> 1;
    if (to >= l2) {
        float4 z = make_float4(0.f, 0.f, 0.f, 0.f);
        #pragma unroll
        for (int i = 0; i < CL_; ++i)
            *(float4*)(obase + (size_t)i * (TO_ * FO_)) = z;
        return;
    }

    // 4x10 input window: rows 2to-1..2to+2, INPUT cols 8f4-1..8f4+8 (zero-padded)
    float w[4][10];
    const float* xb = x + (size_t)b * (T_ * F_);
    const int cbase = 8 * f4;
    #pragma unroll
    for (int i = 0; i < 4; ++i) {
        int r = 2 * to - 1 + i;
        if (r < 0 || r >= T_) {
            #pragma unroll
            for (int j = 0; j < 10; ++j) w[i][j] = 0.f;
        } else {
            const float* rp = xb + r * F_ + cbase;      // 16B-aligned (8*f4 % 4 == 0)
            w[i][0] = (f4 > 0) ? rp[-1] : 0.f;
            float4 m0 = *(const float4*)(rp);
            float4 m1 = *(const float4*)(rp + 4);
            w[i][1] = m0.x; w[i][2] = m0.y; w[i][3] = m0.z; w[i][4] = m0.w;
            w[i][5] = m1.x; w[i][6] = m1.y; w[i][7] = m1.z; w[i][8] = m1.w;
            w[i][9] = (f4 < 9) ? rp[8] : 0.f;
        }
    }

    const float* p = fw + (size_t)bc0 * PSTR_;
    #pragma unroll
    for (int i = 0; i < CL_; ++i) {
        // per-channel filter + bias (wave-uniform address -> L1 broadcast)
        float4 p0 = *(const float4*)(p);
        float4 p1 = *(const float4*)(p + 4);
        float4 p2 = *(const float4*)(p + 8);
        const float Flt[9] = {p0.x, p0.y, p0.z, p0.w, p1.x, p1.y, p1.z, p1.w, p2.x};
        const float bias = p2.y;
        p += PSTR_;

        float o[4];
        #pragma unroll
        for (int q = 0; q < 4; ++q) {
            float s00 = 0.f, s01 = 0.f, s10 = 0.f, s11 = 0.f;
            #pragma unroll
            for (int ii = 0; ii < 3; ++ii) {
                #pragma unroll
                for (int jj = 0; jj < 3; ++jj) {
                    const float flt = Flt[ii * 3 + jj];
                    s00 = fmaf(flt, w[ii][2 * q + jj],     s00);
                    s01 = fmaf(flt, w[ii][2 * q + 1 + jj], s01);
                    s10 = fmaf(flt, w[ii + 1][2 * q + jj],     s10);
                    s11 = fmaf(flt, w[ii + 1][2 * q + 1 + jj], s11);
                }
            }
            float m = fmaxf(fmaxf(s00, s01), fmaxf(s10, s11));
            o[q] = fmaxf(m + bias, 0.f);
        }
        *(float4*)(obase + (size_t)i * (TO_ * FO_)) = make_float4(o[0], o[1], o[2], o[3]);
    }
}

extern "C" void kernel_launch(void* const* d_in, const int* in_sizes, int n_in,
                              void* d_out, int out_size, void* d_ws, size_t ws_size,
                              hipStream_t stream) {
    const float* x     = (const float*)d_in[0];
    const int*   x_len = (const int*)d_in[1];
    const float* aux   = (const float*)d_in[2];
    const float* Wg    = (const float*)d_in[3];
    const float* bg    = (const float*)d_in[4];
    const float* Wb    = (const float*)d_in[5];
    const float* bb    = (const float*)d_in[6];

    float* out = (float*)d_out;
    float* fw  = (float*)d_ws;                        // B*COUT*PSTR_ floats = 98 KB
    float* l2_out = out + (size_t)B_ * COUT_ * TO_ * FO_;  // tail: 32 floats

    // Kernel 1: 18432 + 2048 + 32 = 20512 threads
    {
        int total = B_ * COUT_ * 9 + B_ * COUT_ + B_;
        int blocks = (total + 255) / 256;
        hipLaunchKernelGGL(hyper_kernel, dim3(blocks), dim3(256), 0, stream,
                           aux, Wg, bg, Wb, bb, x_len, fw, l2_out);
    }
    // Kernel 2: exact grid 1,280,000 / 256 = 5000 blocks
    {
        int total = B_ * (COUT_ / CL_) * TO_ * 10;
        int blocks = total / 256;
        hipLaunchKernelGGL(conv_pool_kernel, dim3(blocks), dim3(256), 0, stream,
                           x, x_len, fw, out);
    }
}